// Round 1
// baseline (119.759 us; speedup 1.0000x reference)
//
#include <hip/hip_runtime.h>
#include <hip/hip_bf16.h>
#include <stdint.h>

typedef __attribute__((ext_vector_type(8))) short bf16x8;
typedef __attribute__((ext_vector_type(4))) float f32x4;

#define NB 8192

__device__ __forceinline__ unsigned short f2bf(float f) {
    unsigned int u = __float_as_uint(f);
    u += 0x7fffu + ((u >> 16) & 1u);   // round-to-nearest-even
    return (unsigned short)(u >> 16);
}

__device__ __forceinline__ uint4 pack8(float4 a, float4 b) {
    uint4 r;
    r.x = (unsigned)f2bf(a.x) | ((unsigned)f2bf(a.y) << 16);
    r.y = (unsigned)f2bf(a.z) | ((unsigned)f2bf(a.w) << 16);
    r.z = (unsigned)f2bf(b.x) | ((unsigned)f2bf(b.y) << 16);
    r.w = (unsigned)f2bf(b.z) | ((unsigned)f2bf(b.w) << 16);
    return r;
}

// ---------------------------------------------------------------------------
// prep: W[512][2048] fp32 -> bf16, fragment-linear layout for MFMA B-operand.
// Only k < 1024 is ever used. Fragment (kb,cb), kb,cb in [0,32):
//   uint4 index = (kb*32 + cb)*64 + lane
//   element j (0..7) = W[cb*16 + (lane&15)][kb*32 + (lane>>4)*8 + j]
// ---------------------------------------------------------------------------
__global__ __launch_bounds__(256)
void prep_w_kernel(const float* __restrict__ W, uint4* __restrict__ Wt) {
    int t = blockIdx.x * 256 + threadIdx.x;   // 0..65535
    int lane = t & 63;
    int frag = t >> 6;                         // kb*32 + cb
    int kb = frag >> 5, cb = frag & 31;
    int o = cb * 16 + (lane & 15);
    int k = kb * 32 + ((lane >> 4) << 3);
    const float* src = W + (size_t)o * 2048 + k;
    float4 a = *(const float4*)src;
    float4 b = *(const float4*)(src + 4);
    Wt[t] = pack8(a, b);
}

// ---------------------------------------------------------------------------
// score kernel: grid (64 M-tiles, 6 nodes), 512 threads = 8 waves.
// BM=128, BN=512 (wave w owns cols [w*64, w*64+64)), BK=32.
// ---------------------------------------------------------------------------
__global__ __launch_bounds__(512, 2)
void score_kernel(const float* __restrict__ x0, const float* __restrict__ x1,
                  const float* __restrict__ x2, const float* __restrict__ x3,
                  const float* __restrict__ x4, const float* __restrict__ x5,
                  const float* __restrict__ bias, const float* __restrict__ hvec,
                  const uint4* __restrict__ Wt, float* __restrict__ scores) {
    __shared__ uint4 lA[2][512];      // fragment-linear A tiles, double-buffered
    __shared__ float red[8][128];

    int node = blockIdx.y;
    const float* xp; int dn;
    switch (node) {
        case 0: xp = x0; dn = 1024; break;
        case 1: xp = x1; dn = 512;  break;
        case 2: xp = x2; dn = 512;  break;
        case 3: xp = x3; dn = 512;  break;
        case 4: xp = x4; dn = 1024; break;
        default: xp = x5; dn = 512; break;
    }
    int m0 = blockIdx.x * 128;
    int t = threadIdx.x;
    int lane = t & 63;
    int w = t >> 6;

    // staging address: thread t fills fragment (mf = t>>6, lane = t&63)
    int srow = (t >> 6) * 16 + (lane & 15);
    int scol = (lane >> 4) << 3;
    const float* sp = xp + (size_t)(m0 + srow) * dn + scol;

    int nsteps = dn >> 5;

    // prologue: stage k-step 0 into buffer 0
    {
        float4 a = *(const float4*)sp;
        float4 b = *(const float4*)(sp + 4);
        lA[0][t] = pack8(a, b);
    }
    __syncthreads();

    f32x4 acc[8][4];
#pragma unroll
    for (int mf = 0; mf < 8; ++mf)
#pragma unroll
        for (int nf = 0; nf < 4; ++nf)
            acc[mf][nf] = (f32x4){0.f, 0.f, 0.f, 0.f};

    int cur = 0;
    for (int s = 0; s < nsteps; ++s) {
        // issue next tile's global loads early (overlap with MFMA below)
        float4 na, nb;
        bool hn = (s + 1) < nsteps;
        if (hn) {
            const float* np_ = sp + (s + 1) * 32;
            na = *(const float4*)np_;
            nb = *(const float4*)(np_ + 4);
        }
        // B fragments direct from global (L2-hot, fragment-linear layout)
        const uint4* wp = Wt + ((size_t)((s << 5) + (w << 2)) << 6) + lane;
        bf16x8 bfr[4];
#pragma unroll
        for (int nf = 0; nf < 4; ++nf)
            bfr[nf] = __builtin_bit_cast(bf16x8, wp[nf << 6]);
        // A fragments from LDS (linear -> conflict-free)
        bf16x8 afr[8];
#pragma unroll
        for (int mf = 0; mf < 8; ++mf)
            afr[mf] = __builtin_bit_cast(bf16x8, lA[cur][(mf << 6) + lane]);
#pragma unroll
        for (int mf = 0; mf < 8; ++mf)
#pragma unroll
            for (int nf = 0; nf < 4; ++nf)
                acc[mf][nf] = __builtin_amdgcn_mfma_f32_16x16x32_bf16(
                    afr[mf], bfr[nf], acc[mf][nf], 0, 0, 0);
        if (hn) lA[cur ^ 1][t] = pack8(na, nb);
        __syncthreads();
        cur ^= 1;
    }

    // epilogue: tanh, dot with h, reduce to per-row score
    float bv[4], hv[4];
#pragma unroll
    for (int nf = 0; nf < 4; ++nf) {
        int o = (w << 6) + (nf << 4) + (lane & 15);
        bv[nf] = bias[o];
        hv[nf] = hvec[o];
    }
#pragma unroll
    for (int mf = 0; mf < 8; ++mf) {
        float sc[4] = {0.f, 0.f, 0.f, 0.f};
#pragma unroll
        for (int nf = 0; nf < 4; ++nf) {
#pragma unroll
            for (int r = 0; r < 4; ++r) {
                float xv = acc[mf][nf][r] + bv[nf];
                // tanh(x) = 1 - 2/(1 + e^{2x})
                float th = 1.f - 2.f * __builtin_amdgcn_rcpf(1.f + __expf(2.f * xv));
                sc[r] = fmaf(hv[nf], th, sc[r]);
            }
        }
#pragma unroll
        for (int r = 0; r < 4; ++r) {
            float v = sc[r];
            v += __shfl_xor(v, 1);
            v += __shfl_xor(v, 2);
            v += __shfl_xor(v, 4);
            v += __shfl_xor(v, 8);
            if ((lane & 15) == 0)
                red[w][(mf << 4) + ((lane >> 4) << 2) + r] = v;
        }
    }
    __syncthreads();
    if (t < 128) {
        float ssum = 0.f;
#pragma unroll
        for (int w2 = 0; w2 < 8; ++w2) ssum += red[w2][t];
        scores[node * NB + m0 + t] = ssum;
    }
}

// ---------------------------------------------------------------------------
// z kernel: one wave per batch. softmax over 6 scores, then
// z[0:512]=sum beta_n x_n ; z[512:1024]=b0*ls+b4*ds ; z[1024:2048]=0
// ---------------------------------------------------------------------------
__global__ __launch_bounds__(256)
void z_kernel(const float* __restrict__ x0, const float* __restrict__ x1,
              const float* __restrict__ x2, const float* __restrict__ x3,
              const float* __restrict__ x4, const float* __restrict__ x5,
              const float* __restrict__ scores, float* __restrict__ out) {
    int wv = threadIdx.x >> 6;
    int lane = threadIdx.x & 63;
    int b = (blockIdx.x << 2) + wv;

    float s0 = scores[b];
    float s1 = scores[NB + b];
    float s2 = scores[2 * NB + b];
    float s3 = scores[3 * NB + b];
    float s4 = scores[4 * NB + b];
    float s5 = scores[5 * NB + b];
    float m = fmaxf(fmaxf(fmaxf(s0, s1), fmaxf(s2, s3)), fmaxf(s4, s5));
    float e0 = __expf(s0 - m), e1 = __expf(s1 - m), e2 = __expf(s2 - m);
    float e3 = __expf(s3 - m), e4 = __expf(s4 - m), e5 = __expf(s5 - m);
    float inv = __builtin_amdgcn_rcpf(e0 + e1 + e2 + e3 + e4 + e5);
    float b0 = e0 * inv, b1 = e1 * inv, b2 = e2 * inv;
    float b3 = e3 * inv, b4 = e4 * inv, b5 = e5 * inv;

    const float* pls = x0 + (size_t)b * 1024;
    const float* pA  = x1 + (size_t)b * 512;
    const float* plm = x2 + (size_t)b * 512;
    const float* pAT = x3 + (size_t)b * 512;
    const float* pds = x4 + (size_t)b * 1024;
    const float* pdm = x5 + (size_t)b * 512;
    float* po = out + (size_t)b * 2048;

#pragma unroll
    for (int j = 0; j < 2; ++j) {
        int c = (j << 8) + (lane << 2);
        float4 vls = *(const float4*)(pls + c);
        float4 vA  = *(const float4*)(pA + c);
        float4 vlm = *(const float4*)(plm + c);
        float4 vAT = *(const float4*)(pAT + c);
        float4 vds = *(const float4*)(pds + c);
        float4 vdm = *(const float4*)(pdm + c);
        float4 r;
        r.x = b0*vls.x + b1*vA.x + b2*vlm.x + b3*vAT.x + b4*vds.x + b5*vdm.x;
        r.y = b0*vls.y + b1*vA.y + b2*vlm.y + b3*vAT.y + b4*vds.y + b5*vdm.y;
        r.z = b0*vls.z + b1*vA.z + b2*vlm.z + b3*vAT.z + b4*vds.z + b5*vdm.z;
        r.w = b0*vls.w + b1*vA.w + b2*vlm.w + b3*vAT.w + b4*vds.w + b5*vdm.w;
        *(float4*)(po + c) = r;
    }
#pragma unroll
    for (int j = 0; j < 2; ++j) {
        int c = 512 + (j << 8) + (lane << 2);
        float4 vls = *(const float4*)(pls + c);
        float4 vds = *(const float4*)(pds + c);
        float4 r;
        r.x = b0*vls.x + b4*vds.x;
        r.y = b0*vls.y + b4*vds.y;
        r.z = b0*vls.z + b4*vds.z;
        r.w = b0*vls.w + b4*vds.w;
        *(float4*)(po + c) = r;
    }
    float4 zz = make_float4(0.f, 0.f, 0.f, 0.f);
#pragma unroll
    for (int j = 0; j < 4; ++j) {
        int c = 1024 + (j << 8) + (lane << 2);
        *(float4*)(po + c) = zz;
    }
}

extern "C" void kernel_launch(void* const* d_in, const int* in_sizes, int n_in,
                              void* d_out, int out_size, void* d_ws, size_t ws_size,
                              hipStream_t stream) {
    const float* x0   = (const float*)d_in[0];  // ls  [8192,1024]
    const float* x1   = (const float*)d_in[1];  // A   [8192,512]
    const float* x2   = (const float*)d_in[2];  // lm  [8192,512]
    const float* x3   = (const float*)d_in[3];  // AT  [8192,512]
    const float* x4   = (const float*)d_in[4];  // ds  [8192,1024]
    const float* x5   = (const float*)d_in[5];  // dm  [8192,512]
    const float* W    = (const float*)d_in[6];  // [512,2048]
    const float* bias = (const float*)d_in[7];  // [512]
    const float* hvec = (const float*)d_in[8];  // [512,1]

    uint4* Wt = (uint4*)d_ws;                              // 1 MB
    float* scores = (float*)((char*)d_ws + (1u << 20));    // 6*8192*4 = 192 KB

    prep_w_kernel<<<256, 256, 0, stream>>>(W, Wt);
    dim3 g1(64, 6);
    score_kernel<<<g1, 512, 0, stream>>>(x0, x1, x2, x3, x4, x5, bias, hvec, Wt, scores);
    z_kernel<<<2048, 256, 0, stream>>>(x0, x1, x2, x3, x4, x5, scores, (float*)d_out);
}

// Round 2
// 108.900 us; speedup vs baseline: 1.0997x; 1.0997x over previous
//
#include <hip/hip_runtime.h>
#include <hip/hip_bf16.h>
#include <stdint.h>

typedef __attribute__((ext_vector_type(8))) short bf16x8;
typedef __attribute__((ext_vector_type(4))) float f32x4;

#define NB 8192

__device__ __forceinline__ unsigned short f2bf(float f) {
    unsigned int u = __float_as_uint(f);
    u += 0x7fffu + ((u >> 16) & 1u);   // round-to-nearest-even
    return (unsigned short)(u >> 16);
}

__device__ __forceinline__ uint4 pack8(float4 a, float4 b) {
    uint4 r;
    r.x = (unsigned)f2bf(a.x) | ((unsigned)f2bf(a.y) << 16);
    r.y = (unsigned)f2bf(a.z) | ((unsigned)f2bf(a.w) << 16);
    r.z = (unsigned)f2bf(b.x) | ((unsigned)f2bf(b.y) << 16);
    r.w = (unsigned)f2bf(b.z) | ((unsigned)f2bf(b.w) << 16);
    return r;
}

// ---------------------------------------------------------------------------
// prep: W[512][2048] fp32 -> bf16, fragment-linear layout for MFMA B-operand.
// Only k < 1024 is ever used. Fragment (kb,cb), kb,cb in [0,32):
//   uint4 index = (kb*32 + cb)*64 + lane
//   element j (0..7) = W[cb*16 + (lane&15)][kb*32 + (lane>>4)*8 + j]
// ---------------------------------------------------------------------------
__global__ __launch_bounds__(256)
void prep_w_kernel(const float* __restrict__ W, uint4* __restrict__ Wt) {
    int t = blockIdx.x * 256 + threadIdx.x;   // 0..65535
    int lane = t & 63;
    int frag = t >> 6;                         // kb*32 + cb
    int kb = frag >> 5, cb = frag & 31;
    int o = cb * 16 + (lane & 15);
    int k = kb * 32 + ((lane >> 4) << 3);
    const float* src = W + (size_t)o * 2048 + k;
    float4 a = *(const float4*)src;
    float4 b = *(const float4*)(src + 4);
    Wt[t] = pack8(a, b);
}

// ---------------------------------------------------------------------------
// score kernel: 1D grid of 768 blocks, node = bid % 6 (interleaved so heavy
// dn=1024 nodes spread evenly), row-tile = bid / 6 (BM=64).
// 512 threads = 8 waves; wave w owns cols [w*64, w*64+64): wave tile 64x64,
// acc = 4x4 fragments = 64 VGPR. Target <=128 VGPR -> 2 blocks/CU resident
// so one block's barrier drain overlaps the other's compute.
// ---------------------------------------------------------------------------
__global__ __launch_bounds__(512, 4)
void score_kernel(const float* __restrict__ x0, const float* __restrict__ x1,
                  const float* __restrict__ x2, const float* __restrict__ x3,
                  const float* __restrict__ x4, const float* __restrict__ x5,
                  const float* __restrict__ bias, const float* __restrict__ hvec,
                  const uint4* __restrict__ Wt, float* __restrict__ scores) {
    __shared__ uint4 lA[2][256];      // 64 rows x 32 k bf16, fragment-linear
    __shared__ float red[8][64];

    int bid = blockIdx.x;
    int node = bid % 6;
    int tile = bid / 6;               // 0..127
    const float* xp; int dn;
    switch (node) {
        case 0: xp = x0; dn = 1024; break;
        case 1: xp = x1; dn = 512;  break;
        case 2: xp = x2; dn = 512;  break;
        case 3: xp = x3; dn = 512;  break;
        case 4: xp = x4; dn = 1024; break;
        default: xp = x5; dn = 512; break;
    }
    int m0 = tile * 64;
    int t = threadIdx.x;
    int lane = t & 63;
    int w = t >> 6;

    // staging: thread t loads one float4 -> 4 bf16 (uint2) of fragment
    // (mf = t>>7), lane sl = (t>>1)&63, half h = t&1
    int sl = (t >> 1) & 63;
    int h = t & 1;
    int srow = (t >> 7) * 16 + (sl & 15);
    int scol = ((sl >> 4) << 3) + (h << 2);
    const float* sp = xp + (size_t)(m0 + srow) * dn + scol;

    int nsteps = dn >> 5;

    // prologue: stage k-step 0 into buffer 0
    {
        float4 a = *(const float4*)sp;
        uint2 p;
        p.x = (unsigned)f2bf(a.x) | ((unsigned)f2bf(a.y) << 16);
        p.y = (unsigned)f2bf(a.z) | ((unsigned)f2bf(a.w) << 16);
        ((uint2*)&lA[0][0])[t] = p;
    }
    __syncthreads();

    f32x4 acc[4][4];
#pragma unroll
    for (int mf = 0; mf < 4; ++mf)
#pragma unroll
        for (int nf = 0; nf < 4; ++nf)
            acc[mf][nf] = (f32x4){0.f, 0.f, 0.f, 0.f};

    int cur = 0;
    for (int s = 0; s < nsteps; ++s) {
        // issue next tile's global load early (overlaps with MFMA below)
        float4 na;
        bool hn = (s + 1) < nsteps;
        if (hn) na = *(const float4*)(sp + (s + 1) * 32);

        // B fragments direct from global (L2-hot, fragment-linear layout)
        const uint4* wp = Wt + ((size_t)((s << 5) + (w << 2)) << 6) + lane;
        bf16x8 bfr[4];
#pragma unroll
        for (int nf = 0; nf < 4; ++nf)
            bfr[nf] = __builtin_bit_cast(bf16x8, wp[nf << 6]);
        // A fragments from LDS (linear -> conflict-free)
        bf16x8 afr[4];
#pragma unroll
        for (int mf = 0; mf < 4; ++mf)
            afr[mf] = __builtin_bit_cast(bf16x8, lA[cur][(mf << 6) + lane]);
#pragma unroll
        for (int mf = 0; mf < 4; ++mf)
#pragma unroll
            for (int nf = 0; nf < 4; ++nf)
                acc[mf][nf] = __builtin_amdgcn_mfma_f32_16x16x32_bf16(
                    afr[mf], bfr[nf], acc[mf][nf], 0, 0, 0);
        if (hn) {
            uint2 p;
            p.x = (unsigned)f2bf(na.x) | ((unsigned)f2bf(na.y) << 16);
            p.y = (unsigned)f2bf(na.z) | ((unsigned)f2bf(na.w) << 16);
            ((uint2*)&lA[cur ^ 1][0])[t] = p;
        }
        __syncthreads();
        cur ^= 1;
    }

    // epilogue: tanh, dot with h, reduce to per-row score
    float bv[4], hv[4];
#pragma unroll
    for (int nf = 0; nf < 4; ++nf) {
        int o = (w << 6) + (nf << 4) + (lane & 15);
        bv[nf] = bias[o];
        hv[nf] = hvec[o];
    }
#pragma unroll
    for (int mf = 0; mf < 4; ++mf) {
        float sc[4] = {0.f, 0.f, 0.f, 0.f};
#pragma unroll
        for (int nf = 0; nf < 4; ++nf) {
#pragma unroll
            for (int r = 0; r < 4; ++r) {
                float xv = acc[mf][nf][r] + bv[nf];
                // tanh(x) = 1 - 2/(1 + e^{2x})
                float th = 1.f - 2.f * __builtin_amdgcn_rcpf(1.f + __expf(2.f * xv));
                sc[r] = fmaf(hv[nf], th, sc[r]);
            }
        }
#pragma unroll
        for (int r = 0; r < 4; ++r) {
            float v = sc[r];
            v += __shfl_xor(v, 1);
            v += __shfl_xor(v, 2);
            v += __shfl_xor(v, 4);
            v += __shfl_xor(v, 8);
            if ((lane & 15) == 0)
                red[w][(mf << 4) + ((lane >> 4) << 2) + r] = v;
        }
    }
    __syncthreads();
    if (t < 64) {
        float ssum = 0.f;
#pragma unroll
        for (int w2 = 0; w2 < 8; ++w2) ssum += red[w2][t];
        scores[node * NB + m0 + t] = ssum;
    }
}

// ---------------------------------------------------------------------------
// z kernel: one wave per batch. softmax over 6 scores, then
// z[0:512]=sum beta_n x_n ; z[512:1024]=b0*ls+b4*ds ; z[1024:2048]=0
// ---------------------------------------------------------------------------
__global__ __launch_bounds__(256)
void z_kernel(const float* __restrict__ x0, const float* __restrict__ x1,
              const float* __restrict__ x2, const float* __restrict__ x3,
              const float* __restrict__ x4, const float* __restrict__ x5,
              const float* __restrict__ scores, float* __restrict__ out) {
    int wv = threadIdx.x >> 6;
    int lane = threadIdx.x & 63;
    int b = (blockIdx.x << 2) + wv;

    float s0 = scores[b];
    float s1 = scores[NB + b];
    float s2 = scores[2 * NB + b];
    float s3 = scores[3 * NB + b];
    float s4 = scores[4 * NB + b];
    float s5 = scores[5 * NB + b];
    float m = fmaxf(fmaxf(fmaxf(s0, s1), fmaxf(s2, s3)), fmaxf(s4, s5));
    float e0 = __expf(s0 - m), e1 = __expf(s1 - m), e2 = __expf(s2 - m);
    float e3 = __expf(s3 - m), e4 = __expf(s4 - m), e5 = __expf(s5 - m);
    float inv = __builtin_amdgcn_rcpf(e0 + e1 + e2 + e3 + e4 + e5);
    float b0 = e0 * inv, b1 = e1 * inv, b2 = e2 * inv;
    float b3 = e3 * inv, b4 = e4 * inv, b5 = e5 * inv;

    const float* pls = x0 + (size_t)b * 1024;
    const float* pA  = x1 + (size_t)b * 512;
    const float* plm = x2 + (size_t)b * 512;
    const float* pAT = x3 + (size_t)b * 512;
    const float* pds = x4 + (size_t)b * 1024;
    const float* pdm = x5 + (size_t)b * 512;
    float* po = out + (size_t)b * 2048;

#pragma unroll
    for (int j = 0; j < 2; ++j) {
        int c = (j << 8) + (lane << 2);
        float4 vls = *(const float4*)(pls + c);
        float4 vA  = *(const float4*)(pA + c);
        float4 vlm = *(const float4*)(plm + c);
        float4 vAT = *(const float4*)(pAT + c);
        float4 vds = *(const float4*)(pds + c);
        float4 vdm = *(const float4*)(pdm + c);
        float4 r;
        r.x = b0*vls.x + b1*vA.x + b2*vlm.x + b3*vAT.x + b4*vds.x + b5*vdm.x;
        r.y = b0*vls.y + b1*vA.y + b2*vlm.y + b3*vAT.y + b4*vds.y + b5*vdm.y;
        r.z = b0*vls.z + b1*vA.z + b2*vlm.z + b3*vAT.z + b4*vds.z + b5*vdm.z;
        r.w = b0*vls.w + b1*vA.w + b2*vlm.w + b3*vAT.w + b4*vds.w + b5*vdm.w;
        *(float4*)(po + c) = r;
    }
#pragma unroll
    for (int j = 0; j < 2; ++j) {
        int c = 512 + (j << 8) + (lane << 2);
        float4 vls = *(const float4*)(pls + c);
        float4 vds = *(const float4*)(pds + c);
        float4 r;
        r.x = b0*vls.x + b4*vds.x;
        r.y = b0*vls.y + b4*vds.y;
        r.z = b0*vls.z + b4*vds.z;
        r.w = b0*vls.w + b4*vds.w;
        *(float4*)(po + c) = r;
    }
    float4 zz = make_float4(0.f, 0.f, 0.f, 0.f);
#pragma unroll
    for (int j = 0; j < 4; ++j) {
        int c = 1024 + (j << 8) + (lane << 2);
        *(float4*)(po + c) = zz;
    }
}

extern "C" void kernel_launch(void* const* d_in, const int* in_sizes, int n_in,
                              void* d_out, int out_size, void* d_ws, size_t ws_size,
                              hipStream_t stream) {
    const float* x0   = (const float*)d_in[0];  // ls  [8192,1024]
    const float* x1   = (const float*)d_in[1];  // A   [8192,512]
    const float* x2   = (const float*)d_in[2];  // lm  [8192,512]
    const float* x3   = (const float*)d_in[3];  // AT  [8192,512]
    const float* x4   = (const float*)d_in[4];  // ds  [8192,1024]
    const float* x5   = (const float*)d_in[5];  // dm  [8192,512]
    const float* W    = (const float*)d_in[6];  // [512,2048]
    const float* bias = (const float*)d_in[7];  // [512]
    const float* hvec = (const float*)d_in[8];  // [512,1]

    uint4* Wt = (uint4*)d_ws;                              // 1 MB
    float* scores = (float*)((char*)d_ws + (1u << 20));    // 6*8192*4 = 192 KB

    prep_w_kernel<<<256, 256, 0, stream>>>(W, Wt);
    score_kernel<<<768, 512, 0, stream>>>(x0, x1, x2, x3, x4, x5, bias, hvec, Wt, scores);
    z_kernel<<<2048, 256, 0, stream>>>(x0, x1, x2, x3, x4, x5, scores, (float*)d_out);
}